// Round 13
// baseline (109.020 us; speedup 1.0000x reference)
//
#include <hip/hip_runtime.h>
#include <hip/hip_bf16.h>

#define BATCH 4096
#define NROWS 8192
#define DIM   128
#define NTILE 64
#define NBLK  4160   // sum over rb of (2rb+2) half-tiles (128 rows x 64 cols)

typedef __bf16 bf16x8 __attribute__((ext_vector_type(8)));
typedef __bf16 bf16x2 __attribute__((ext_vector_type(2)));
typedef float  f32x4  __attribute__((ext_vector_type(4)));

typedef const __attribute__((address_space(1))) unsigned int* gptr_t;
typedef __attribute__((address_space(3))) unsigned int* lptr_t;

// ---------------------------------------------------------------------------
// Kernel 1: row-normalize z = concat(zx, zy) -> bf16 zn [8192 x 128].
// One wave per row. Zeroes S (blocks 0..31) and out (block 0).
// ---------------------------------------------------------------------------
__global__ __launch_bounds__(256) void normalize_kernel(
    const float* __restrict__ zx, const float* __restrict__ zy,
    ushort* __restrict__ zn, float* __restrict__ S, float* __restrict__ out)
{
  const int tid  = threadIdx.x;
  const int lane = tid & 63;
  const int w    = tid >> 6;
  const int row  = blockIdx.x * 4 + w;
  if (blockIdx.x < 32) S[blockIdx.x * 256 + tid] = 0.f;
  if (blockIdx.x == 0 && tid == 0) out[0] = 0.f;
  const float* src = (row < BATCH) ? (zx + (size_t)row * DIM)
                                   : (zy + (size_t)(row - BATCH) * DIM);
  float2 v = ((const float2*)src)[lane];
  float ss = v.x * v.x + v.y * v.y;
#pragma unroll
  for (int off = 1; off < 64; off <<= 1)
    ss += __shfl_xor(ss, off, 64);
  float inv = 1.0f / fmaxf(sqrtf(ss), 1e-8f);
  bf16x2 st;
  st.x = (__bf16)(v.x * inv);
  st.y = (__bf16)(v.y * inv);
  reinterpret_cast<bf16x2*>(zn + (size_t)row * DIM)[lane] = st;
}

// ---------------------------------------------------------------------------
// Kernel 2 (v12): MANY SMALL INDEPENDENT BLOCKS — one 128x64 half-tile each.
// Every prior schedule (staged/LDS-free/8-wave/atomic-free) pinned at ~28-37us
// with all pipes <10% busy: per-tile-slot latency that only independent
// BLOCKS can hide (barriers lockstep waves within a block). v12: 4160 blocks
// (~16/CU), 4 RESIDENT blocks/CU (VGPR ~110 <= 128 via acc[2][4]+af[2][4];
// LDS 16 KiB), no sequential tile chain, ONE barrier per block.
//
// Coverage (sim symmetric, lower triangle in 128x64 granularity):
//   tile (rb, c'), c' <= 2rb+1. Strict-lower (c'>>1 < rb): row-side sums
//   (rows of rb-block over these 64 cols) AND col-side sums (cols as rows).
//   Diag half-tiles (c'>>1 == rb): row-side only (the two halves' row-sides
//   cover the whole diagonal block; self-diagonal zeroed via gcol==grow).
//   Positive halves (rb>=32, c'>>1 == rb-32): write P[gr] and mirror.
// All sums -> S[8192] via shfl-reduce + atomicAdd (S pre-zeroed).
// Bijective chunked XCD swizzle: XCD x owns virtual tiles [x*520,(x+1)*520)
// = contiguous rb-runs -> A rows + B panels (<=2.2 MiB) stay L2-warm.
// ---------------------------------------------------------------------------
__global__ __launch_bounds__(256, 4) void simloss_kernel(
    const ushort* __restrict__ zn, float* __restrict__ S,
    float* __restrict__ P)
{
  __shared__ ushort Bs[64 * 128];   // 16 KiB swizzled B half-tile
  const int tid  = threadIdx.x;
  const int lane = tid & 63;
  const int w    = tid >> 6;       // wave 0..3: rows w*32..+32 of the tile
  const int q    = lane >> 4;      // quad 0..3
  const int l15  = lane & 15;

  // Bijective chunked XCD swizzle (4160 = 8 x 520).
  const int v = (blockIdx.x & 7) * 520 + (blockIdx.x >> 3);

  // Decode (rb, c'): rb*(rb+1) <= v < (rb+1)*(rb+2).
  int rb;
  {
    int lo = 0, hi = NTILE - 1;
    while (lo < hi) {
      int mid = (lo + hi + 1) >> 1;
      if (mid * (mid + 1) <= v) lo = mid; else hi = mid - 1;
    }
    rb = lo;
  }
  const int cp = v - rb * (rb + 1);          // 0 .. 2rb+1
  const int c0 = cp * 64;                    // global col base
  const bool diag = ((cp >> 1) == rb);
  const bool pos  = (rb >= 32) && ((cp >> 1) == rb - 32);

  // Stage B half-tile: 64 rows (cols c0..c0+63) x 128 K = 1024 16B-chunks.
  // Chunk (row, c) -> LDS chunk row*16 + (c ^ (row&15)); dest is uniform
  // base + lane*16, swizzle applied on the per-lane GLOBAL source address.
#pragma unroll
  for (int j = 0; j < 4; ++j) {
    const int Lbase = j * 256 + w * 64;            // uniform per wave
    const int row   = j * 16 + w * 4 + q;          // (Lbase+lane)>>4
    const int c     = l15 ^ (row & 15);
    const ushort* g = zn + (size_t)(c0 + row) * DIM + c * 8;
    __builtin_amdgcn_global_load_lds((gptr_t)g, (lptr_t)(Bs + Lbase * 8), 16, 0, 0);
  }

  // A fragments: rows rb*128 + w*32 + mi*16 + l15 (mi 0..1), k = ks*32+q*8
  bf16x8 af[2][4];
  {
    const int arow = rb * 128 + w * 32 + l15;
#pragma unroll
    for (int mi = 0; mi < 2; ++mi)
#pragma unroll
      for (int ks = 0; ks < 4; ++ks) {
        const ushort* ap = zn + (size_t)(arow + mi * 16) * DIM + ks * 32 + q * 8;
        af[mi][ks] = *reinterpret_cast<const bf16x8*>(ap);
      }
  }

  __syncthreads();   // B staged (compiler drains vmcnt(0) before s_barrier)

  f32x4 acc[2][4];
#pragma unroll
  for (int mi = 0; mi < 2; ++mi)
#pragma unroll
    for (int ni = 0; ni < 4; ++ni)
      acc[mi][ni] = (f32x4){0.f, 0.f, 0.f, 0.f};

#pragma unroll
  for (int ks = 0; ks < 4; ++ks) {
    bf16x8 bf[4];
#pragma unroll
    for (int ni = 0; ni < 4; ++ni) {
      const int nl = ni * 16 + l15;              // B row in tile (sim col)
      const int ck = ks * 4 + q;                 // k-chunk 0..15
      const int L  = nl * 16 + (ck ^ (nl & 15));
      bf[ni] = *reinterpret_cast<const bf16x8*>(Bs + L * 8);
    }
#pragma unroll
    for (int mi = 0; mi < 2; ++mi)
#pragma unroll
      for (int ni = 0; ni < 4; ++ni)
        acc[mi][ni] = __builtin_amdgcn_mfma_f32_16x16x32_bf16(
            af[mi][ks], bf[ni], acc[mi][ni], 0, 0, 0);
  }

  // Epilogue: val = exp(sim - 2) = exp2(K1*dot - K1).
  const float K1 = 2.8853900817779268f;  // (1/TEMP) * log2(e)
  f32x4 Srow[2];
  float Scol[4];
#pragma unroll
  for (int mi = 0; mi < 2; ++mi) Srow[mi] = (f32x4){0.f, 0.f, 0.f, 0.f};
#pragma unroll
  for (int ni = 0; ni < 4; ++ni) Scol[ni] = 0.f;

#pragma unroll
  for (int mi = 0; mi < 2; ++mi)
#pragma unroll
    for (int ni = 0; ni < 4; ++ni) {
      f32x4 vv;
#pragma unroll
      for (int r = 0; r < 4; ++r) {
        const int rl   = w * 32 + mi * 16 + q * 4 + r;   // row in rb-block
        const int grow = rb * 128 + rl;
        const int gcol = c0 + ni * 16 + l15;
        float d = acc[mi][ni][r];
        float val = __builtin_amdgcn_exp2f(fmaf(d, K1, -K1));
        if (diag && gcol == grow) val = 0.f;
        vv[r] = val;
        if (pos && gcol == grow - 4096) {
          const float pv = 2.0f * d;
          P[grow] = pv;
          P[grow - 4096] = pv;   // symmetric partner
        }
      }
      Srow[mi] += vv;
      Scol[ni] += (vv[0] + vv[1]) + (vv[2] + vv[3]);
    }

  // Row-side flush: reduce over l15; lanes l15==0 (q=0..3) atomicAdd.
#pragma unroll
  for (int mi = 0; mi < 2; ++mi)
#pragma unroll
    for (int r = 0; r < 4; ++r) {
      float s = Srow[mi][r];
      s += __shfl_xor(s, 1, 64);
      s += __shfl_xor(s, 2, 64);
      s += __shfl_xor(s, 4, 64);
      s += __shfl_xor(s, 8, 64);
      if (l15 == 0)
        atomicAdd(&S[rb * 128 + w * 32 + mi * 16 + q * 4 + r], s);
    }

  // Col-side flush (strict-lower tiles only): reduce over quads (the wave's
  // 32 rows); lanes<16 atomicAdd; the 4 waves' partials combine in S.
  if (!diag) {
#pragma unroll
    for (int ni = 0; ni < 4; ++ni) {
      float s = Scol[ni];
      s += __shfl_xor(s, 16, 64);
      s += __shfl_xor(s, 32, 64);
      if (lane < 16)
        atomicAdd(&S[c0 + ni * 16 + l15], s);
    }
  }
}

// ---------------------------------------------------------------------------
// Kernel 3: loss = mean_i( 2 + log(S_i) - P_i ); out zeroed by normalize.
// ---------------------------------------------------------------------------
__global__ __launch_bounds__(256) void finalize_kernel(
    const float* __restrict__ S, const float* __restrict__ P,
    float* __restrict__ out)
{
  const int i = blockIdx.x * 256 + threadIdx.x;
  float c = 2.0f + logf(S[i]) - P[i];
#pragma unroll
  for (int off = 1; off < 64; off <<= 1)
    c += __shfl_xor(c, off, 64);
  __shared__ float wsum[4];
  const int lane = threadIdx.x & 63, w = threadIdx.x >> 6;
  if (lane == 0) wsum[w] = c;
  __syncthreads();
  if (threadIdx.x == 0)
    atomicAdd(out, (wsum[0] + wsum[1] + wsum[2] + wsum[3]) * (1.0f / NROWS));
}

// ---------------------------------------------------------------------------
extern "C" void kernel_launch(void* const* d_in, const int* in_sizes, int n_in,
                              void* d_out, int out_size, void* d_ws, size_t ws_size,
                              hipStream_t stream)
{
  const float* zx = (const float*)d_in[0];
  const float* zy = (const float*)d_in[1];
  ushort* zn = (ushort*)d_ws;                                      // 2 MiB bf16
  float*  P  = (float*)((char*)d_ws + (size_t)NROWS * DIM * 2);    // 32 KiB
  float*  S  = P + NROWS;                                          // 32 KiB
  float*  out = (float*)d_out;

  normalize_kernel<<<NROWS / 4, 256, 0, stream>>>(zx, zy, zn, S, out);
  simloss_kernel<<<NBLK, 256, 0, stream>>>(zn, S, P);
  finalize_kernel<<<NROWS / 256, 256, 0, stream>>>(S, P, out);
}